// Round 2
// baseline (76.933 us; speedup 1.0000x reference)
//
#include <hip/hip_runtime.h>
#include <hip/hip_bf16.h>

// FreqCounter: out[b,i] = lookup[item_ids[b,i]]
// item_ids: (16384, 1000) int32 (harness passes integer inputs as int*)
// lookup:   (120000,) float32 — 480 KB, L2-resident
// out:      (16384, 1000) float32
// user_ids (d_in[0]) unused, matching the reference forward.
//
// Latency-bound gather: maximize memory-level parallelism. Each thread owns
// U=4 int4 quads (16 elements), block-strided so every load instruction is
// wave-coalesced. Fully unrolled: 4 id-loads in flight, then 16 independent
// gathers, then 4 stores. No grid-stride loop (unique mapping) so there is
// no loop-carried vmcnt serialization.

#define UNROLL 4

__global__ void FreqCounter_68315749810839_kernel(
    const int* __restrict__ ids,
    const float* __restrict__ lookup,
    float* __restrict__ out,
    long n4)  // number of int4/float4 quads
{
    const int4* __restrict__ ids4 = (const int4*)ids;
    float4* __restrict__ out4 = (float4*)out;

    // Block tile: blockDim.x * UNROLL quads; thread t touches tile + t + u*blockDim.x
    long tile = (long)blockIdx.x * (blockDim.x * UNROLL) + threadIdx.x;

    int4 v[UNROLL];
    bool ok[UNROLL];
#pragma unroll
    for (int u = 0; u < UNROLL; ++u) {
        long idx = tile + (long)u * blockDim.x;
        ok[u] = idx < n4;
        v[u] = ok[u] ? ids4[idx] : make_int4(0, 0, 0, 0);
    }

    float4 r[UNROLL];
#pragma unroll
    for (int u = 0; u < UNROLL; ++u) {
        r[u].x = lookup[v[u].x];
        r[u].y = lookup[v[u].y];
        r[u].z = lookup[v[u].z];
        r[u].w = lookup[v[u].w];
    }

#pragma unroll
    for (int u = 0; u < UNROLL; ++u) {
        long idx = tile + (long)u * blockDim.x;
        if (ok[u]) out4[idx] = r[u];
    }
}

extern "C" void kernel_launch(void* const* d_in, const int* in_sizes, int n_in,
                              void* d_out, int out_size, void* d_ws, size_t ws_size,
                              hipStream_t stream) {
    // setup_inputs order: user_ids, item_ids, lookup
    const int*   ids    = (const int*)d_in[1];
    const float* lookup = (const float*)d_in[2];
    float*       out    = (float*)d_out;

    const long n = (long)in_sizes[1];      // 16,384,000 — divisible by 4
    const long n4 = n / 4;

    const int block = 256;
    const long quads_per_block = (long)block * UNROLL;
    long grid = (n4 + quads_per_block - 1) / quads_per_block;  // 4000 for this shape

    FreqCounter_68315749810839_kernel<<<(int)grid, block, 0, stream>>>(ids, lookup, out, n4);
}

// Round 3
// 76.884 us; speedup vs baseline: 1.0006x; 1.0006x over previous
//
#include <hip/hip_runtime.h>
#include <hip/hip_bf16.h>

// FreqCounter: out[b,i] = lookup[item_ids[b,i]]
// item_ids: (16384, 1000) int32, lookup: (120000,) f32 (480 KB, L2-resident),
// out: (16384, 1000) f32. user_ids (d_in[0]) unused.
//
// Latency/request-rate-bound random gather. Key change this round: gathers
// use agent-scope loads (__hip_atomic_load RELAXED/AGENT) -> L1 bypass.
// The table misses L1 ~93% of the time anyway; bypassing skips the L1
// tag-probe + 64B line-fill serialization per lane and goes straight to the
// XCD L2, where the 480 KB table is fully resident.

#define BLOCK 256
#define UNROLL 4

__device__ __forceinline__ float gatherL2(const float* __restrict__ p) {
    return __hip_atomic_load(p, __ATOMIC_RELAXED, __HIP_MEMORY_SCOPE_AGENT);
}

__global__ void __launch_bounds__(BLOCK)
FreqCounter_68315749810839_kernel(
    const int* __restrict__ ids,
    const float* __restrict__ lookup,
    float* __restrict__ out)
{
    const int4* __restrict__ ids4 = (const int4*)ids;
    float4* __restrict__ out4 = (float4*)out;

    // Exact tiling: grid * BLOCK * UNROLL quads, no bounds checks here.
    long tile = (long)blockIdx.x * (BLOCK * UNROLL) + threadIdx.x;

    int4 v[UNROLL];
#pragma unroll
    for (int u = 0; u < UNROLL; ++u)
        v[u] = ids4[tile + u * BLOCK];

    float4 r[UNROLL];
#pragma unroll
    for (int u = 0; u < UNROLL; ++u) {
        r[u].x = gatherL2(&lookup[v[u].x]);
        r[u].y = gatherL2(&lookup[v[u].y]);
        r[u].z = gatherL2(&lookup[v[u].z]);
        r[u].w = gatherL2(&lookup[v[u].w]);
    }

#pragma unroll
    for (int u = 0; u < UNROLL; ++u)
        out4[tile + u * BLOCK] = r[u];
}

// Tail: one element per thread, bounds-checked (only launched if needed).
__global__ void FreqCounter_tail_kernel(
    const int* __restrict__ ids,
    const float* __restrict__ lookup,
    float* __restrict__ out,
    long start, long n)
{
    long i = start + (long)blockIdx.x * blockDim.x + threadIdx.x;
    if (i < n) out[i] = gatherL2(&lookup[ids[i]]);
}

extern "C" void kernel_launch(void* const* d_in, const int* in_sizes, int n_in,
                              void* d_out, int out_size, void* d_ws, size_t ws_size,
                              hipStream_t stream) {
    // setup_inputs order: user_ids, item_ids, lookup
    const int*   ids    = (const int*)d_in[1];
    const float* lookup = (const float*)d_in[2];
    float*       out    = (float*)d_out;

    const long n  = (long)in_sizes[1];   // 16,384,000
    const long n4 = n / 4;               // 4,096,000 quads
    const long quads_per_block = (long)BLOCK * UNROLL;  // 1024
    const long full_blocks = n4 / quads_per_block;      // 4000 (exact here)

    if (full_blocks > 0)
        FreqCounter_68315749810839_kernel<<<(int)full_blocks, BLOCK, 0, stream>>>(
            ids, lookup, out);

    const long done = full_blocks * quads_per_block * 4;
    const long rem = n - done;
    if (rem > 0) {
        int tgrid = (int)((rem + BLOCK - 1) / BLOCK);
        FreqCounter_tail_kernel<<<tgrid, BLOCK, 0, stream>>>(ids, lookup, out, done, n);
    }
}

// Round 4
// 50.587 us; speedup vs baseline: 1.5208x; 1.5198x over previous
//
#include <hip/hip_runtime.h>
#include <hip/hip_bf16.h>

// FreqCounter: out[b,i] = lookup[item_ids[b,i]]
// item_ids: (16384, 1000) int32, lookup: (120000,) f32, out: f32.
// user_ids (d_in[0]) unused.
//
// The random gather over the 480 KB table saturates the per-CU VMEM
// address path (~3 cy/lane measured, identical with and without L1
// bypass). This version services the gathers from LDS instead:
//  - table split into 4 slices of <=30720 floats (120 KB dynamic LDS)
//  - each block: ids+results live in registers across all 4 slice passes
//    (2 generations x 8 int4 quads/thread, <=128 VGPR so 16 waves/CU)
//  - per slice: cooperative stage -> barrier -> unconditional ds_read
//    probes with out-of-slice lanes clamped to addr 0 (broadcast = free)
//    -> cndmask select -> barrier
//  - one fully-coalesced float4 store per quad at the end.

#define BLOCK 1024
#define QCHUNK 8                 // int4 quads per thread per generation
#define SLICE_ENTRIES 30720      // floats per LDS slice = 122880 B
#define GRID 256

__global__ void __launch_bounds__(BLOCK, 4)
FreqCounter_68315749810839_kernel(
    const int* __restrict__ ids,
    const float* __restrict__ lookup,
    float* __restrict__ out,
    long n4, long qpb, int T)
{
    extern __shared__ float lds[];
    const int tid = threadIdx.x;
    const int4* __restrict__ ids4 = (const int4*)ids;
    float4* __restrict__ out4 = (float4*)out;

    const long base = (long)blockIdx.x * qpb;
    if (base >= n4) return;                       // block-uniform
    const long qend0 = base + qpb;
    const long qend = qend0 < n4 ? qend0 : n4;
    const long gens = (qpb + (long)(BLOCK * QCHUNK) - 1) / (BLOCK * QCHUNK);

    for (long g = 0; g < gens; ++g) {
        const long gbase = base + g * (BLOCK * QCHUNK);

        int4 v[QCHUNK];
        float4 r[QCHUNK];
        bool ok[QCHUNK];
#pragma unroll
        for (int q = 0; q < QCHUNK; ++q) {
            long idx = gbase + tid + (long)q * BLOCK;
            ok[q] = idx < qend;
            v[q] = ok[q] ? ids4[idx] : make_int4(0, 0, 0, 0);
            r[q] = make_float4(0.f, 0.f, 0.f, 0.f);
        }

        for (int s = 0; s * SLICE_ENTRIES < T; ++s) {
            const int lo = s * SLICE_ENTRIES;
            const int rem = T - lo;
            const int len = rem < SLICE_ENTRIES ? rem : SLICE_ENTRIES;

            // ---- stage slice into LDS (coalesced float4) ----
            const int len4 = len >> 2;
            const float4* __restrict__ lk4 = (const float4*)(lookup + lo);
            float4* lds4 = (float4*)lds;
            for (int j = tid; j < len4; j += BLOCK) lds4[j] = lk4[j];
            if (tid < (len & 3))
                lds[(len4 << 2) + tid] = lookup[lo + (len4 << 2) + tid];
            __syncthreads();

            // ---- probe: unconditional ds_read, OOS lanes -> addr 0 ----
#define PROBE(comp)                                                     \
            {                                                           \
                unsigned d = (unsigned)v[q].comp - (unsigned)lo;        \
                bool in = d < (unsigned)len;                            \
                float val = lds[in ? (int)d : 0];                       \
                if (in) r[q].comp = val;                                \
            }
#pragma unroll
            for (int q = 0; q < QCHUNK; ++q) {
                PROBE(x) PROBE(y) PROBE(z) PROBE(w)
            }
#undef PROBE
            __syncthreads();   // before next slice overwrites LDS
        }

#pragma unroll
        for (int q = 0; q < QCHUNK; ++q) {
            long idx = gbase + tid + (long)q * BLOCK;
            if (ok[q]) out4[idx] = r[q];
        }
    }
}

// Scalar tail for n % 4 (not hit for this shape, kept for generality).
__global__ void FreqCounter_tail_kernel(
    const int* __restrict__ ids,
    const float* __restrict__ lookup,
    float* __restrict__ out,
    long start, long n)
{
    long i = start + (long)blockIdx.x * blockDim.x + threadIdx.x;
    if (i < n) out[i] = lookup[ids[i]];
}

extern "C" void kernel_launch(void* const* d_in, const int* in_sizes, int n_in,
                              void* d_out, int out_size, void* d_ws, size_t ws_size,
                              hipStream_t stream) {
    // setup_inputs order: user_ids, item_ids, lookup
    const int*   ids    = (const int*)d_in[1];
    const float* lookup = (const float*)d_in[2];
    float*       out    = (float*)d_out;

    const long n  = (long)in_sizes[1];     // 16,384,000
    const int  T  = in_sizes[2];           // 120,000 table entries
    const long n4 = n / 4;                 // 4,096,000 quads

    const size_t smem = (size_t)SLICE_ENTRIES * sizeof(float);  // 122880 B
    // Allow >64 KB dynamic LDS (host-side, idempotent, capture-safe).
    (void)hipFuncSetAttribute(
        reinterpret_cast<const void*>(FreqCounter_68315749810839_kernel),
        hipFuncAttributeMaxDynamicSharedMemorySize, (int)smem);

    const long qpb = (n4 + GRID - 1) / GRID;   // quads per block (16000)
    FreqCounter_68315749810839_kernel<<<GRID, BLOCK, smem, stream>>>(
        ids, lookup, out, n4, qpb, T);

    const long done = n4 * 4;
    if (done < n) {
        long rem = n - done;
        int tgrid = (int)((rem + 255) / 256);
        FreqCounter_tail_kernel<<<tgrid, 256, 0, stream>>>(ids, lookup, out, done, n);
    }
}